// Round 7
// baseline (148.911 us; speedup 1.0000x reference)
//
#include <hip/hip_runtime.h>
#include <hip/hip_bf16.h>

#define NN 2048
typedef unsigned short us;
typedef __attribute__((ext_vector_type(8))) short short8;
typedef __attribute__((ext_vector_type(4))) float f4;
typedef __attribute__((ext_vector_type(4))) float f32x4;
typedef __attribute__((ext_vector_type(8))) unsigned short us8;

__device__ __forceinline__ us f2bf(float f) {
    unsigned int u = __float_as_uint(f);
    u += 0x7fffu + ((u >> 16) & 1u);   // RNE
    return (us)(u >> 16);
}
__device__ __forceinline__ float bf2f(us h) {
    return __uint_as_float(((unsigned int)h) << 16);
}
__device__ __forceinline__ void gload16(const us* g, us* l) {
    __builtin_amdgcn_global_load_lds(
        (const __attribute__((address_space(1))) unsigned int*)g,
        (__attribute__((address_space(3))) unsigned int*)l, 16, 0, 0);
}

// ---------------------------------------------------------------------------
// K1: prep. Block (I,J): Bbf tile(I,J) + BbfT tile(J,I) via LDS transpose.
//     Diag blocks: t1 partial, zero rs/cs; block(0,0): zero t2 accumulator.
// ---------------------------------------------------------------------------
__global__ void prep_kernel(const float* __restrict__ A0,
                            us* __restrict__ Bbf, us* __restrict__ BbfT,
                            float* __restrict__ rs, float* __restrict__ cs,
                            double* __restrict__ pt1, double* __restrict__ accs) {
    __shared__ float sq[64][65];
    const int I = blockIdx.y, J = blockIdx.x;
    const int tid = threadIdx.x, lane = tid & 63, wv = tid >> 6;
    const size_t rI = (size_t)I * 64, rJ = (size_t)J * 64;

    #pragma unroll
    for (int u = tid; u < 512; u += 256) {
        const int row = u >> 3, c8 = (u & 7) * 8;
        f4 a0 = *(const f4*)&A0[(rI + row) * NN + rJ + c8];
        f4 a1 = *(const f4*)&A0[(rI + row) * NN + rJ + c8 + 4];
        us8 o;
        #pragma unroll
        for (int k = 0; k < 4; ++k) { float s = a0[k] * a0[k]; sq[row][c8 + k] = s; o[k] = f2bf(s); }
        #pragma unroll
        for (int k = 0; k < 4; ++k) { float s = a1[k] * a1[k]; sq[row][c8 + 4 + k] = s; o[4 + k] = f2bf(s); }
        *(us8*)&Bbf[(rI + row) * NN + rJ + c8] = o;
    }
    __syncthreads();

    #pragma unroll
    for (int u = tid; u < 512; u += 256) {
        const int r = u >> 3, c0 = (u & 7) * 8;
        us8 o;
        #pragma unroll
        for (int k = 0; k < 8; ++k) o[k] = f2bf(sq[c0 + k][r]);   // 2-way bank, free
        *(us8*)&BbfT[(rJ + r) * NN + rI + c0] = o;
    }

    if (I == J) {
        if (tid < 64) { rs[rI + tid] = 0.f; cs[rI + tid] = 0.f; }
        if (I == 0 && tid == 64) accs[0] = 0.0;
        if (wv == 0) {
            double t1 = sq[lane][lane];
            #pragma unroll
            for (int s = 32; s > 0; s >>= 1) t1 += __shfl_down(t1, s, 64);
            if (lane == 0) pt1[I] = t1;
        }
    }
}

// ---------------------------------------------------------------------------
// K2: split-K=4 GEMM, m97-style single-buffered (4 blocks/CU for implicit
//     inter-block overlap). z covers K = z*512..+512. bf16 part outputs,
//     fused exact rs/cs, fused t2 = tr(C2) on diagonal blocks.
// ---------------------------------------------------------------------------
__launch_bounds__(256, 4)
__global__ void gemm_kernel(const us* __restrict__ A, const us* __restrict__ BT,
                            us* __restrict__ c2, float* __restrict__ rs,
                            float* __restrict__ cs, double* __restrict__ accs) {
    __shared__ us lA[4096];
    __shared__ us lB[4096];
    const int tid  = threadIdx.x;
    const int lane = tid & 63;
    const int w    = tid >> 6;
    const int wr   = w >> 1, wc = w & 1;
    const int rowBase = blockIdx.y * 128;
    const int colBase = blockIdx.x * 128;
    const int kbase   = blockIdx.z * 512;
    us* __restrict__ C = c2 + (size_t)blockIdx.z * (NN * (size_t)NN);
    const int lr = lane & 15;
    const int lk = (lane >> 4) * 8;

    const int srow = tid >> 2;
    const int scol = (tid & 3) * 8;
    const us* gA0 = A  + (size_t)(rowBase + srow) * NN + kbase + scol;
    const us* gA1 = A  + (size_t)(rowBase + 64 + srow) * NN + kbase + scol;
    const us* gB0 = BT + (size_t)(colBase + srow) * NN + kbase + scol;
    const us* gB1 = BT + (size_t)(colBase + 64 + srow) * NN + kbase + scol;
    const int d0 = srow * 32 + scol;
    const int d1 = (64 + srow) * 32 + scol;

    f32x4 acc[4][4] = {};

    for (int t = 0; t < 16; ++t) {
        const int k = t * 32;
        gload16(gA0 + k, &lA[d0]);
        gload16(gA1 + k, &lA[d1]);
        gload16(gB0 + k, &lB[d0]);
        gload16(gB1 + k, &lB[d1]);
        __syncthreads();                     // drains vmcnt (global_load_lds)

        short8 af[4], bfr[4];
        #pragma unroll
        for (int mi = 0; mi < 4; ++mi)
            af[mi] = *(const short8*)&lA[(wr * 64 + mi * 16 + lr) * 32 + lk];
        #pragma unroll
        for (int ni = 0; ni < 4; ++ni)
            bfr[ni] = *(const short8*)&lB[(wc * 64 + ni * 16 + lr) * 32 + lk];
        #pragma unroll
        for (int mi = 0; mi < 4; ++mi)
            #pragma unroll
            for (int ni = 0; ni < 4; ++ni)
                acc[mi][ni] = __builtin_amdgcn_mfma_f32_16x16x32_bf16(
                    af[mi], bfr[ni], acc[mi][ni], 0, 0, 0);
        __syncthreads();
    }

    // epilogue: bf16 part write, exact fp32 rs/cs, t2 diag on diagonal blocks
    const int orow = (lane >> 4) * 4;
    const int ocol = lane & 15;
    const bool diagblk = (rowBase == colBase);
    double tdiag = 0.0;
    float colp[4] = {0.f, 0.f, 0.f, 0.f};
    #pragma unroll
    for (int mi = 0; mi < 4; ++mi) {
        #pragma unroll
        for (int r = 0; r < 4; ++r) {
            const int gr = rowBase + wr * 64 + mi * 16 + orow + r;
            float rowp = 0.f;
            #pragma unroll
            for (int ni = 0; ni < 4; ++ni) {
                float v = acc[mi][ni][r];
                const int gc = colBase + wc * 64 + ni * 16 + ocol;
                C[(size_t)gr * NN + gc] = f2bf(v);
                rowp += v;
                colp[ni] += v;
                if (diagblk && gr == gc) tdiag += (double)v;
            }
            rowp += __shfl_xor(rowp, 1, 64);
            rowp += __shfl_xor(rowp, 2, 64);
            rowp += __shfl_xor(rowp, 4, 64);
            rowp += __shfl_xor(rowp, 8, 64);
            if ((lane & 15) == 0) atomicAdd(&rs[gr], rowp);
        }
    }
    #pragma unroll
    for (int ni = 0; ni < 4; ++ni) {
        colp[ni] += __shfl_xor(colp[ni], 16, 64);
        colp[ni] += __shfl_xor(colp[ni], 32, 64);
        if (lane < 16) atomicAdd(&cs[colBase + wc * 64 + ni * 16 + ocol], colp[ni]);
    }
    if (diagblk) {
        #pragma unroll
        for (int s = 32; s > 0; s >>= 1) tdiag += __shfl_down(tdiag, s, 64);
        if (lane == 0 && tdiag != 0.0) atomicAdd(&accs[0], tdiag);
    }
}

// ---------------------------------------------------------------------------
// K3: corr. Block (I,J): t3 = <C2,BbfT> (elementwise, coalesced),
//     t4 = <C2(I,J), C2(J,I)^T> via one LDS transpose tile. C2 = sum 4 parts.
// ---------------------------------------------------------------------------
__global__ void corr_kernel(const us* __restrict__ c2,
                            const us* __restrict__ BbfT,
                            double* __restrict__ pt3, double* __restrict__ pt4) {
    __shared__ float cT[64][65];
    __shared__ double wred[2][4];
    const size_t PS = (size_t)NN * NN;     // elems per part
    const int I = blockIdx.y, J = blockIdx.x;
    const int tid = threadIdx.x, lane = tid & 63, wv = tid >> 6;
    const size_t rI = (size_t)I * 64, rJ = (size_t)J * 64;

    double t3 = 0;
    float myC[2][8];
    #pragma unroll
    for (int ph = 0; ph < 2; ++ph) {
        const int u = tid + ph * 256;
        const int row = u >> 3, c8 = (u & 7) * 8;
        const size_t off  = (rI + row) * NN + rJ + c8;
        const size_t off2 = (rJ + row) * NN + rI + c8;
        us8 v0 = *(const us8*)&c2[off];
        us8 v1 = *(const us8*)&c2[off + PS];
        us8 v2 = *(const us8*)&c2[off + 2 * PS];
        us8 v3 = *(const us8*)&c2[off + 3 * PS];
        us8 vt = *(const us8*)&BbfT[off];
        us8 w0 = *(const us8*)&c2[off2];
        us8 w1 = *(const us8*)&c2[off2 + PS];
        us8 w2 = *(const us8*)&c2[off2 + 2 * PS];
        us8 w3 = *(const us8*)&c2[off2 + 3 * PS];
        #pragma unroll
        for (int k = 0; k < 8; ++k) {
            float c = (bf2f(v0[k]) + bf2f(v1[k])) + (bf2f(v2[k]) + bf2f(v3[k]));
            myC[ph][k] = c;
            t3 += (double)(c * bf2f(vt[k]));
            cT[row][c8 + k] = (bf2f(w0[k]) + bf2f(w1[k])) + (bf2f(w2[k]) + bf2f(w3[k]));
        }
    }
    __syncthreads();

    double t4 = 0;
    #pragma unroll
    for (int ph = 0; ph < 2; ++ph) {
        const int u = tid + ph * 256;
        const int row = u >> 3, c8 = (u & 7) * 8;
        #pragma unroll
        for (int k = 0; k < 8; ++k)
            t4 += (double)(myC[ph][k] * cT[c8 + k][row]);   // 2-way bank, free
    }

    #pragma unroll
    for (int s = 32; s > 0; s >>= 1) {
        t3 += __shfl_down(t3, s, 64);
        t4 += __shfl_down(t4, s, 64);
    }
    if (lane == 0) { wred[0][wv] = t3; wred[1][wv] = t4; }
    __syncthreads();
    if (tid == 0) {
        const int b = blockIdx.y * 32 + blockIdx.x;
        pt3[b] = wred[0][0] + wred[0][1] + wred[0][2] + wred[0][3];
        pt4[b] = wred[1][0] + wred[1][1] + wred[1][2] + wred[1][3];
    }
}

// ---------------------------------------------------------------------------
// K4: combine. lam^2 = (rs.cs)/sum(rs); h = t1 + t2/2 + t3/6 + t4/24 + tail
// ---------------------------------------------------------------------------
__global__ void finalize_kernel(const float* __restrict__ rs,
                                const float* __restrict__ cs,
                                const double* __restrict__ pt1,
                                const double* __restrict__ accs,
                                const double* __restrict__ pt3,
                                const double* __restrict__ pt4,
                                float* __restrict__ out) {
    __shared__ double red[256];
    const int t = threadIdx.x;
    double t1 = 0, t3 = 0, t4 = 0, s2 = 0, s4 = 0;
    if (t < 32) t1 = pt1[t];
    for (int i = t; i < 1024; i += 256) { t3 += pt3[i]; t4 += pt4[i]; }
    for (int i = t; i < NN; i += 256) {
        double r = rs[i];
        s2 += r; s4 += r * (double)cs[i];
    }
    double vals[5] = {t1, t3, t4, s2, s4};
    double tot[5];
    for (int v = 0; v < 5; ++v) {
        red[t] = vals[v]; __syncthreads();
        for (int s = 128; s > 0; s >>= 1) { if (t < s) red[t] += red[t + s]; __syncthreads(); }
        tot[v] = red[0]; __syncthreads();
    }
    if (t == 0) {
        double t2 = accs[0];
        double lam2 = tot[4] / tot[3];
        double lam  = sqrt(lam2);
        double tail = exp(lam) - 1.0 - lam - lam2 * 0.5
                      - lam * lam2 * (1.0 / 6.0) - lam2 * lam2 * (1.0 / 24.0);
        out[0] = (float)(tot[0] + t2 * 0.5 + tot[1] * (1.0 / 6.0)
                         + tot[2] * (1.0 / 24.0) + tail);
    }
}

// ---------------------------------------------------------------------------
extern "C" void kernel_launch(void* const* d_in, const int* in_sizes, int n_in,
                              void* d_out, int out_size, void* d_ws, size_t ws_size,
                              hipStream_t stream) {
    const float* A0 = (const float*)d_in[0];     // contemporaneous slice [2048,2048]
    char* ws = (char*)d_ws;
    us*     Bbf  = (us*)(ws);                    //  8 MB bf16 B
    us*     BbfT = (us*)(ws + 8388608);          //  8 MB bf16 B^T
    us*     c2   = (us*)(ws + 16777216);         // 32 MB: 4 bf16 parts of B^2
    float*  rs   = (float*)(ws + 50331648);      //  8 KB rowsums of B^2
    float*  cs   = (float*)(ws + 50339840);      //  8 KB colsums of B^2
    double* pt1  = (double*)(ws + 50348032);     //  32 partials (t1)
    double* accs = (double*)(ws + 50348544);     //  t2 accumulator
    double* pt3  = (double*)(ws + 50349056);     //  1024 partials each
    double* pt4  = (double*)(ws + 50357248);
    float*  out  = (float*)d_out;

    prep_kernel<<<dim3(32, 32), 256, 0, stream>>>(A0, Bbf, BbfT, rs, cs, pt1, accs);
    gemm_kernel<<<dim3(16, 16, 4), 256, 0, stream>>>(Bbf, BbfT, c2, rs, cs, accs);
    corr_kernel<<<dim3(32, 32), 256, 0, stream>>>(c2, BbfT, pt3, pt4);
    finalize_kernel<<<1, 256, 0, stream>>>(rs, cs, pt1, accs, pt3, pt4, out);
}

// Round 10
// 139.442 us; speedup vs baseline: 1.0679x; 1.0679x over previous
//
#include <hip/hip_runtime.h>
#include <hip/hip_bf16.h>

#define NN 2048
typedef unsigned short us;
typedef __attribute__((ext_vector_type(8))) short short8;
typedef __attribute__((ext_vector_type(4))) float f4;
typedef __attribute__((ext_vector_type(4))) float f32x4;
typedef __attribute__((ext_vector_type(8))) unsigned short us8;
typedef __attribute__((ext_vector_type(4))) unsigned short us4;

__device__ __forceinline__ us f2bf(float f) {
    unsigned int u = __float_as_uint(f);
    u += 0x7fffu + ((u >> 16) & 1u);   // RNE
    return (us)(u >> 16);
}
__device__ __forceinline__ float bf2f(us h) {
    return __uint_as_float(((unsigned int)h) << 16);
}
__device__ __forceinline__ void gload16(const us* g, us* l) {
    __builtin_amdgcn_global_load_lds(
        (const __attribute__((address_space(1))) unsigned int*)g,
        (__attribute__((address_space(3))) unsigned int*)l, 16, 0, 0);
}

// ---------------------------------------------------------------------------
// K1: prep. Block (I,J): Bbf tile(I,J) + BbfT tile(J,I) via LDS transpose.
//     Diag blocks: t1 partial, zero rsD/csD; block(0,0): zero t2 accumulator.
// ---------------------------------------------------------------------------
__global__ void prep_kernel(const float* __restrict__ A0,
                            us* __restrict__ Bbf, us* __restrict__ BbfT,
                            float* __restrict__ rsD, float* __restrict__ csD,
                            double* __restrict__ pt1, double* __restrict__ accs) {
    __shared__ float sq[64][65];
    const int I = blockIdx.y, J = blockIdx.x;
    const int tid = threadIdx.x, lane = tid & 63, wv = tid >> 6;
    const size_t rI = (size_t)I * 64, rJ = (size_t)J * 64;

    #pragma unroll
    for (int u = tid; u < 512; u += 256) {
        const int row = u >> 3, c8 = (u & 7) * 8;
        f4 a0 = *(const f4*)&A0[(rI + row) * NN + rJ + c8];
        f4 a1 = *(const f4*)&A0[(rI + row) * NN + rJ + c8 + 4];
        us8 o;
        #pragma unroll
        for (int k = 0; k < 4; ++k) { float s = a0[k] * a0[k]; sq[row][c8 + k] = s; o[k] = f2bf(s); }
        #pragma unroll
        for (int k = 0; k < 4; ++k) { float s = a1[k] * a1[k]; sq[row][c8 + 4 + k] = s; o[4 + k] = f2bf(s); }
        *(us8*)&Bbf[(rI + row) * NN + rJ + c8] = o;
    }
    __syncthreads();

    #pragma unroll
    for (int u = tid; u < 512; u += 256) {
        const int r = u >> 3, c0 = (u & 7) * 8;
        us8 o;
        #pragma unroll
        for (int k = 0; k < 8; ++k) o[k] = f2bf(sq[c0 + k][r]);   // 2-way bank, free
        *(us8*)&BbfT[(rJ + r) * NN + rI + c0] = o;
    }

    if (I == J) {
        if (tid < 64) { rsD[rI + tid] = 0.f; csD[rI + tid] = 0.f; }
        if (I == 0 && tid == 64) accs[0] = 0.0;
        if (wv == 0) {
            double t1 = sq[lane][lane];
            #pragma unroll
            for (int s = 32; s > 0; s >>= 1) t1 += __shfl_down(t1, s, 64);
            if (lane == 0) pt1[I] = t1;
        }
    }
}

// ---------------------------------------------------------------------------
// K2: split-K=4 GEMM, double-buffered, 4 blocks/CU (32KB LDS, VGPR<=128).
//     Writes D_z = (partial B^2)^T as bf16 (us4 transposed stores).
//     Fused t2 = tr(B^2) on diagonal blocks.
// ---------------------------------------------------------------------------
__launch_bounds__(256, 4)
__global__ void gemm_kernel(const us* __restrict__ A, const us* __restrict__ BT,
                            us* __restrict__ D, double* __restrict__ accs) {
    __shared__ us lA[2][4096];
    __shared__ us lB[2][4096];
    const int tid  = threadIdx.x;
    const int lane = tid & 63;
    const int w    = tid >> 6;
    const int wr   = w >> 1, wc = w & 1;
    const int rowBase = blockIdx.y * 128;
    const int colBase = blockIdx.x * 128;
    const int kbase   = blockIdx.z * 512;
    us* __restrict__ Dp = D + (size_t)blockIdx.z * ((size_t)NN * NN);
    const int lr = lane & 15;
    const int lk = (lane >> 4) * 8;

    const int srow = tid >> 2;
    const int scol = (tid & 3) * 8;
    const us* gA0 = A  + (size_t)(rowBase + srow) * NN + kbase + scol;
    const us* gA1 = A  + (size_t)(rowBase + 64 + srow) * NN + kbase + scol;
    const us* gB0 = BT + (size_t)(colBase + srow) * NN + kbase + scol;
    const us* gB1 = BT + (size_t)(colBase + 64 + srow) * NN + kbase + scol;
    const int d0 = srow * 32 + scol;
    const int d1 = (64 + srow) * 32 + scol;

    f32x4 acc[4][4] = {};

    gload16(gA0, &lA[0][d0]);
    gload16(gA1, &lA[0][d1]);
    gload16(gB0, &lB[0][d0]);
    gload16(gB1, &lB[0][d1]);
    __syncthreads();

    for (int t = 0; t < 16; ++t) {
        const int cur = t & 1;
        if (t < 15) {                        // prefetch t+1 into buf^1
            const int k = (t + 1) * 32;
            gload16(gA0 + k, &lA[cur ^ 1][d0]);
            gload16(gA1 + k, &lA[cur ^ 1][d1]);
            gload16(gB0 + k, &lB[cur ^ 1][d0]);
            gload16(gB1 + k, &lB[cur ^ 1][d1]);
        }
        short8 af[4], bfr[4];
        #pragma unroll
        for (int mi = 0; mi < 4; ++mi)
            af[mi] = *(const short8*)&lA[cur][(wr * 64 + mi * 16 + lr) * 32 + lk];
        #pragma unroll
        for (int ni = 0; ni < 4; ++ni)
            bfr[ni] = *(const short8*)&lB[cur][(wc * 64 + ni * 16 + lr) * 32 + lk];
        #pragma unroll
        for (int mi = 0; mi < 4; ++mi)
            #pragma unroll
            for (int ni = 0; ni < 4; ++ni)
                acc[mi][ni] = __builtin_amdgcn_mfma_f32_16x16x32_bf16(
                    af[mi], bfr[ni], acc[mi][ni], 0, 0, 0);
        __syncthreads();                     // drains prefetch; buf^1 ready
    }

    // epilogue: D[gc][gr0..gr0+3] = acc (us4, 8B per fragment), + t2 diag
    const int orow = (lane >> 4) * 4;
    const int ocol = lane & 15;
    const bool diagblk = (rowBase == colBase);
    double tdiag = 0.0;
    #pragma unroll
    for (int mi = 0; mi < 4; ++mi)
        #pragma unroll
        for (int ni = 0; ni < 4; ++ni) {
            const int gr0 = rowBase + wr * 64 + mi * 16 + orow;
            const int gc  = colBase + wc * 64 + ni * 16 + ocol;
            us4 o;
            #pragma unroll
            for (int r = 0; r < 4; ++r) o[r] = f2bf(acc[mi][ni][r]);
            *(us4*)&Dp[(size_t)gc * NN + gr0] = o;
            if (diagblk) {
                #pragma unroll
                for (int r = 0; r < 4; ++r)
                    if (gc == gr0 + r) tdiag += (double)acc[mi][ni][r];
            }
        }
    if (diagblk) {
        #pragma unroll
        for (int s = 32; s > 0; s >>= 1) tdiag += __shfl_down(tdiag, s, 64);
        if (lane == 0) atomicAdd(&accs[0], tdiag);
    }
}

// ---------------------------------------------------------------------------
// K3: corr on D = (B^2)^T (4 bf16 parts). Block (I,J):
//     t3 = <D, B> elementwise (both row-major, coalesced!),
//     t4 = <D(I,J), D(J,I)^T> via LDS transpose tile,
//     rsD/csD = row/col sums of D (8-lane reductions, distributed atomics).
// ---------------------------------------------------------------------------
__global__ void corr_kernel(const us* __restrict__ D, const us* __restrict__ Bbf,
                            float* __restrict__ rsD, float* __restrict__ csD,
                            double* __restrict__ pt3, double* __restrict__ pt4) {
    __shared__ float dT[64][65];
    __shared__ double wred[2][4];
    const size_t PS = (size_t)NN * NN;
    const int I = blockIdx.y, J = blockIdx.x;
    const int tid = threadIdx.x, lane = tid & 63, wv = tid >> 6;
    const size_t rI = (size_t)I * 64, rJ = (size_t)J * 64;

    double t3 = 0;
    float myD[2][8];
    float rowp[2];
    #pragma unroll
    for (int ph = 0; ph < 2; ++ph) {
        const int u = tid + ph * 256;
        const int row = u >> 3, c8 = (u & 7) * 8;
        const size_t off  = (rI + row) * NN + rJ + c8;
        const size_t off2 = (rJ + row) * NN + rI + c8;
        us8 v0 = *(const us8*)&D[off];
        us8 v1 = *(const us8*)&D[off + PS];
        us8 v2 = *(const us8*)&D[off + 2 * PS];
        us8 v3 = *(const us8*)&D[off + 3 * PS];
        us8 vb = *(const us8*)&Bbf[off];
        us8 w0 = *(const us8*)&D[off2];
        us8 w1 = *(const us8*)&D[off2 + PS];
        us8 w2 = *(const us8*)&D[off2 + 2 * PS];
        us8 w3 = *(const us8*)&D[off2 + 3 * PS];
        float rp = 0.f;
        #pragma unroll
        for (int k = 0; k < 8; ++k) {
            float d = (bf2f(v0[k]) + bf2f(v1[k])) + (bf2f(v2[k]) + bf2f(v3[k]));
            myD[ph][k] = d;
            rp += d;
            t3 += (double)(d * bf2f(vb[k]));
            dT[row][c8 + k] = (bf2f(w0[k]) + bf2f(w1[k])) + (bf2f(w2[k]) + bf2f(w3[k]));
        }
        rowp[ph] = rp;
    }
    __syncthreads();

    double t4 = 0;
    float colp[2];
    #pragma unroll
    for (int ph = 0; ph < 2; ++ph) {
        const int u = tid + ph * 256;
        const int row = u >> 3, c8 = (u & 7) * 8;
        float cp = 0.f;
        #pragma unroll
        for (int k = 0; k < 8; ++k) {
            float x = dT[c8 + k][row];
            t4 += (double)(myD[ph][k] * x);
            cp += x;
        }
        colp[ph] = cp;
    }

    // 8-lane reductions -> per-row atomics (rows rI+row; distributed)
    #pragma unroll
    for (int ph = 0; ph < 2; ++ph) {
        float rp = rowp[ph], cp = colp[ph];
        rp += __shfl_xor(rp, 1, 64); rp += __shfl_xor(rp, 2, 64); rp += __shfl_xor(rp, 4, 64);
        cp += __shfl_xor(cp, 1, 64); cp += __shfl_xor(cp, 2, 64); cp += __shfl_xor(cp, 4, 64);
        const int row = (tid + ph * 256) >> 3;
        if ((tid & 7) == 0) {
            atomicAdd(&rsD[rI + row], rp);
            atomicAdd(&csD[rI + row], cp);
        }
    }

    #pragma unroll
    for (int s = 32; s > 0; s >>= 1) {
        t3 += __shfl_down(t3, s, 64);
        t4 += __shfl_down(t4, s, 64);
    }
    if (lane == 0) { wred[0][wv] = t3; wred[1][wv] = t4; }
    __syncthreads();
    if (tid == 0) {
        const int b = blockIdx.y * 32 + blockIdx.x;
        pt3[b] = wred[0][0] + wred[0][1] + wred[0][2] + wred[0][3];
        pt4[b] = wred[1][0] + wred[1][1] + wred[1][2] + wred[1][3];
    }
}

// ---------------------------------------------------------------------------
// K4: combine. rowsum(B^2) = csD, colsum(B^2) = rsD; lam^2 = (rsD.csD)/sum;
//     h = t1 + t2/2 + t3/6 + t4/24 + rank-1 tail
// ---------------------------------------------------------------------------
__global__ void finalize_kernel(const float* __restrict__ rsD,
                                const float* __restrict__ csD,
                                const double* __restrict__ pt1,
                                const double* __restrict__ accs,
                                const double* __restrict__ pt3,
                                const double* __restrict__ pt4,
                                float* __restrict__ out) {
    __shared__ double red[256];
    const int t = threadIdx.x;
    double t1 = 0, t3 = 0, t4 = 0, s2 = 0, s4 = 0;
    if (t < 32) t1 = pt1[t];
    for (int i = t; i < 1024; i += 256) { t3 += pt3[i]; t4 += pt4[i]; }
    for (int i = t; i < NN; i += 256) {
        double r = rsD[i];
        s2 += r; s4 += r * (double)csD[i];
    }
    double vals[5] = {t1, t3, t4, s2, s4};
    double tot[5];
    for (int v = 0; v < 5; ++v) {
        red[t] = vals[v]; __syncthreads();
        for (int s = 128; s > 0; s >>= 1) { if (t < s) red[t] += red[t + s]; __syncthreads(); }
        tot[v] = red[0]; __syncthreads();
    }
    if (t == 0) {
        double t2 = accs[0];
        double lam2 = tot[4] / tot[3];
        double lam  = sqrt(lam2);
        double tail = exp(lam) - 1.0 - lam - lam2 * 0.5
                      - lam * lam2 * (1.0 / 6.0) - lam2 * lam2 * (1.0 / 24.0);
        out[0] = (float)(tot[0] + t2 * 0.5 + tot[1] * (1.0 / 6.0)
                         + tot[2] * (1.0 / 24.0) + tail);
    }
}

// ---------------------------------------------------------------------------
extern "C" void kernel_launch(void* const* d_in, const int* in_sizes, int n_in,
                              void* d_out, int out_size, void* d_ws, size_t ws_size,
                              hipStream_t stream) {
    const float* A0 = (const float*)d_in[0];     // contemporaneous slice [2048,2048]
    char* ws = (char*)d_ws;
    us*     Bbf  = (us*)(ws);                    //  8 MB bf16 B
    us*     BbfT = (us*)(ws + 8388608);          //  8 MB bf16 B^T (gemm B-operand)
    us*     Dmat = (us*)(ws + 16777216);         // 32 MB: 4 bf16 parts of (B^2)^T
    float*  rsD  = (float*)(ws + 50331648);      //  8 KB rowsums of D
    float*  csD  = (float*)(ws + 50339840);      //  8 KB colsums of D
    double* pt1  = (double*)(ws + 50348032);     //  32 partials (t1)
    double* accs = (double*)(ws + 50348544);     //  t2 accumulator
    double* pt3  = (double*)(ws + 50349056);     //  1024 partials each
    double* pt4  = (double*)(ws + 50357248);
    float*  out  = (float*)d_out;

    prep_kernel<<<dim3(32, 32), 256, 0, stream>>>(A0, Bbf, BbfT, rsD, csD, pt1, accs);
    gemm_kernel<<<dim3(16, 16, 4), 256, 0, stream>>>(Bbf, BbfT, Dmat, accs);
    corr_kernel<<<dim3(32, 32), 256, 0, stream>>>(Dmat, Bbf, rsD, csD, pt3, pt4);
    finalize_kernel<<<1, 256, 0, stream>>>(rsD, csD, pt1, accs, pt3, pt4, out);
}